// Round 6
// baseline (32162.546 us; speedup 1.0000x reference)
//
#include <hip/hip_runtime.h>
#include <math.h>

#define N_PTS 32768
#define M_SEL 8192
#define K_NBR 64
#define F_IN  64
#define H_MID 128
#define C_OUT 128
#define NCELL 512   // 8x8x8 grid
#define CAP   192   // per-centroid candidate cap
#define NW    4     // waves in fps block
#define NT    (NW * 64)

// ---------- helpers ----------

__device__ __forceinline__ int clamp8(int v) { return v < 0 ? 0 : (v > 7 ? 7 : v); }

__device__ __forceinline__ int cell_of(float px, float py, float pz) {
    int ix = clamp8((int)(px * 8.0f));
    int iy = clamp8((int)(py * 8.0f));
    int iz = clamp8((int)(pz * 8.0f));
    return (iz * 8 + iy) * 8 + ix;
}

// Bit-exact replica of numpy: ((dx*dx + dy*dy) + dz*dz), rn, no fma.
__device__ __forceinline__ float d2_exact(float ax, float ay, float az,
                                          float bx, float by, float bz) {
#pragma clang fp contract(off)
    float dx = ax - bx, dy = ay - by, dz = az - bz;
    return (dx * dx + dy * dy) + dz * dz;
}

__device__ __forceinline__ unsigned long long umax64(unsigned long long a,
                                                     unsigned long long b) {
    return a > b ? a : b;
}

// ---------- binning ----------

__global__ void bin_count_kernel(const float* __restrict__ pos, int* __restrict__ cnt) {
    int i = blockIdx.x * blockDim.x + threadIdx.x;
    if (i < N_PTS) {
        atomicAdd(&cnt[cell_of(pos[3*i], pos[3*i+1], pos[3*i+2])], 1);
    }
}

__global__ void scan_kernel(const int* __restrict__ cnt, int* __restrict__ start,
                            int* __restrict__ fill) {
    __shared__ int s[NCELL];
    int t = threadIdx.x;
    int v = cnt[t];
    s[t] = v;
    __syncthreads();
    for (int off = 1; off < NCELL; off <<= 1) {
        int add = (t >= off) ? s[t - off] : 0;
        __syncthreads();
        s[t] += add;
        __syncthreads();
    }
    int ex = s[t] - v;           // exclusive scan
    start[t] = ex;
    fill[t]  = ex;
    if (t == NCELL - 1) start[NCELL] = s[t];
}

// pq[slot] = (x, y, z, orig_index_as_float_bits) — one dwordx4 per point
__global__ void scatter_kernel(const float* __restrict__ pos, int* __restrict__ fill,
                               float4* __restrict__ pq) {
    int i = blockIdx.x * blockDim.x + threadIdx.x;
    if (i < N_PTS) {
        float px = pos[3*i], py = pos[3*i+1], pz = pos[3*i+2];
        int c = cell_of(px, py, pz);
        int slot = atomicAdd(&fill[c], 1);
        pq[slot] = make_float4(px, py, pz, __int_as_float(i));
    }
}

// ---------- FPS ----------
// 256 threads (4 waves). mind[] LDS-resident. Flagged cells -> compact per-wave
// lists (ballot-rank scatter). B-phase: 8 lane-groups of 8 per wave process 8
// cells concurrently (pipelined loads). Per-cell max via 2 u64 sub-slots
// (ds_max_u64, 4-way contention). Replicated argmax via 8-slot LDS atomic
// tree. 2 barriers/iteration.

__global__ __launch_bounds__(NT) void fps_kernel(
        const float4* __restrict__ pq, const int* __restrict__ cstart,
        const float* __restrict__ pos, int* __restrict__ sel) {
    __shared__ float s_mind[N_PTS];                       // 128 KB
    __shared__ unsigned long long s_sub[NCELL][2];        // 8 KB
    __shared__ unsigned long long s_best[NCELL];          // 4 KB
    __shared__ unsigned long long s_redw[NW][8];          // 256 B
    __shared__ int s_cs[NCELL + 1];
    __shared__ short s_wlist[NW][NCELL];                  // 4 KB

    const int tid  = threadIdx.x;
    const int lane = tid & 63;
    const int wid  = tid >> 6;
    const int g    = lane >> 3;     // lane-group 0..7
    const int gl   = lane & 7;      // lane within group
    const unsigned long long lmask_lt = (1ULL << lane) - 1ULL;

    for (int i = tid; i < N_PTS; i += NT) s_mind[i] = INFINITY;
    for (int i = tid; i < NCELL + 1; i += NT) s_cs[i] = cstart[i];
    for (int c = tid; c < NCELL; c += NT)
        s_best[c] = (cstart[c + 1] > cstart[c])
                    ? ((0x7F800000ULL << 32) | 0xFFFFFFFFULL) : 0ULL;
    if (tid == 0) sel[0] = 0;
    __syncthreads();

    // per-lane cell geometry (cells lane + 64k)
    float lox[8], loy[8], loz[8];
    #pragma unroll
    for (int k = 0; k < 8; ++k) {
        const int c = lane + (k << 6);
        lox[k] = (float)(c & 7)        * 0.125f;
        loy[k] = (float)((c >> 3) & 7) * 0.125f;
        loz[k] = (float)(c >> 6)       * 0.125f;
    }

    unsigned long long vb[8];     // current per-cell best (replicated view)
    unsigned long long fm[8];     // flag masks (identical in all waves)
    int nw = 0;                   // this wave's list length
    float px = pos[0], py = pos[1], pz = pos[2];

    #pragma unroll
    for (int k = 0; k < 8; ++k) vb[k] = s_best[lane + (k << 6)];

    auto flag_assign = [&]() {
        unsigned int cum = 0, cw0 = 0, cw1 = 0, cw2 = 0, cw3 = 0;
        #pragma unroll
        for (int k = 0; k < 8; ++k) {
            const float cm = __uint_as_float((unsigned int)(vb[k] >> 32));
            float dx = fmaxf(fmaxf(lox[k] - px, px - (lox[k] + 0.125f)), 0.0f);
            float dy = fmaxf(fmaxf(loy[k] - py, py - (loy[k] + 0.125f)), 0.0f);
            float dz = fmaxf(fmaxf(loz[k] - pz, pz - (loz[k] + 0.125f)), 0.0f);
            float lb2 = dx * dx + dy * dy + dz * dz;
            bool fl = (lb2 * 0.999f < cm);               // conservative skip bound
            unsigned long long b = __ballot(fl);
            fm[k] = b;
            unsigned int rank = cum + (unsigned int)__popcll(b & lmask_lt);
            unsigned int wc = rank & (NW - 1);
            unsigned long long b0 = __ballot(fl && wc == 0);
            unsigned long long b1 = __ballot(fl && wc == 1);
            unsigned long long b2 = __ballot(fl && wc == 2);
            unsigned long long b3 = __ballot(fl && wc == 3);
            if (fl && wc == (unsigned)wid) {
                unsigned long long bw = (wid == 0) ? b0 : (wid == 1) ? b1
                                       : (wid == 2) ? b2 : b3;
                unsigned int cw = (wid == 0) ? cw0 : (wid == 1) ? cw1
                                 : (wid == 2) ? cw2 : cw3;
                unsigned int idx = cw + (unsigned int)__popcll(bw & lmask_lt);
                s_wlist[wid][idx] = (short)(lane + (k << 6));
            }
            cw0 += (unsigned int)__popcll(b0);
            cw1 += (unsigned int)__popcll(b1);
            cw2 += (unsigned int)__popcll(b2);
            cw3 += (unsigned int)__popcll(b3);
            cum += (unsigned int)__popcll(b);
        }
        nw = (wid == 0) ? (int)cw0 : (wid == 1) ? (int)cw1
             : (wid == 2) ? (int)cw2 : (int)cw3;
    };
    flag_assign();
    __syncthreads();

    for (int m = 1; m < M_SEL; ++m) {
        // ---- B: 8 cells in flight per wave (one per lane-group) ----
        if (lane < 8) s_redw[wid][lane] = 0ULL;          // reset own reduce slots
        for (int i = g; i < nw; i += 8) {
            const int c = s_wlist[wid][i];
            if (gl < 2) s_sub[c][gl] = 0ULL;             // in-order before atomics
            const int cs = s_cs[c], ce = s_cs[c + 1];
            for (int j = cs + gl; j < ce; j += 8) {
                const float4 q  = pq[j];
                const float d2  = d2_exact(q.x, q.y, q.z, px, py, pz);
                const float old = s_mind[j];
                const float nv  = d2 < old ? d2 : old;
                s_mind[j] = nv;
                const unsigned long long pk =
                    ((unsigned long long)__float_as_uint(nv) << 32)
                    | (unsigned long long)(~(unsigned int)__float_as_int(q.w));
                atomicMax(&s_sub[c][gl >> 2], pk);
            }
        }
        __syncthreads();

        // ---- D: consolidate flagged cells, replicated argmax over 512 ----
        unsigned long long best = 0ULL;
        #pragma unroll
        for (int k = 0; k < 8; ++k) {
            const int c = lane + (k << 6);
            unsigned long long v;
            if ((fm[k] >> lane) & 1ULL) {
                v = umax64(s_sub[c][0], s_sub[c][1]);
                if (wid == 0) s_best[c] = v;             // persist for later iters
            } else {
                v = s_best[c];
            }
            vb[k] = v;
            best = umax64(best, v);
        }
        atomicMax(&s_redw[wid][lane & 7], best);         // intra-wave, in-order
        #pragma unroll
        for (int i = 0; i < 8; ++i) best = umax64(best, s_redw[wid][i]);

        const unsigned int orig = ~(unsigned int)best;
        if (tid == 0) sel[m] = (int)orig;
        px = pos[3 * orig]; py = pos[3 * orig + 1]; pz = pos[3 * orig + 2];

        // ---- F: flags + per-wave lists for next iteration ----
        flag_assign();
        __syncthreads();     // D/F reads done before next B's writes
    }
}

// ---------- ball query: up-to-64 nearest in-radius (one wave / centroid) ----------

__global__ __launch_bounds__(256) void ballq_kernel(
        const float* __restrict__ pos,
        const float4* __restrict__ pq,
        const int* __restrict__ cstart, const int* __restrict__ sel,
        int* __restrict__ nbr, int* __restrict__ ncnt) {
    __shared__ float s_d2[4][CAP];
    __shared__ int   s_o[4][CAP];
    __shared__ int   s_cnt[4];

    const int wid  = threadIdx.x >> 6;
    const int lane = threadIdx.x & 63;
    const int m = blockIdx.x * 4 + wid;

    if (lane == 0) s_cnt[wid] = 0;
    __syncthreads();

    int sidx = sel[m];
    float cx = pos[3*sidx], cy = pos[3*sidx+1], cz = pos[3*sidx+2];
    int ix = clamp8((int)(cx * 8.0f));
    int iy = clamp8((int)(cy * 8.0f));
    int iz = clamp8((int)(cz * 8.0f));
    const float r2 = (float)(0.08 * 0.08);

    for (int dz = -1; dz <= 1; ++dz) {
        int z = iz + dz; if (z < 0 || z > 7) continue;
        for (int dy = -1; dy <= 1; ++dy) {
            int y = iy + dy; if (y < 0 || y > 7) continue;
            for (int dx = -1; dx <= 1; ++dx) {
                int xq = ix + dx; if (xq < 0 || xq > 7) continue;
                int c = (z * 8 + y) * 8 + xq;
                int cs = cstart[c], ce = cstart[c + 1];
                for (int j = cs + lane; j < ce; j += 64) {
                    float4 q = pq[j];
                    float d2 = d2_exact(cx, cy, cz, q.x, q.y, q.z);
                    if (d2 <= r2) {
                        int slot = atomicAdd(&s_cnt[wid], 1);
                        if (slot < CAP) { s_d2[wid][slot] = d2; s_o[wid][slot] = __float_as_int(q.w); }
                    }
                }
            }
        }
    }
    __syncthreads();

    int cnt = s_cnt[wid];
    if (cnt > CAP) cnt = CAP;
    if (cnt <= K_NBR) {
        if (lane < cnt) nbr[m * K_NBR + lane] = s_o[wid][lane];
        if (lane == 0) ncnt[m] = cnt;
    } else {
        // exact (d2, orig-index) lexicographic rank -> keep 64 nearest (matches top_k)
        for (int i = lane; i < cnt; i += 64) {
            float d2 = s_d2[wid][i];
            int   o  = s_o[wid][i];
            int rank = 0;
            for (int j = 0; j < cnt; ++j) {
                float dj = s_d2[wid][j];
                int   oj = s_o[wid][j];
                rank += (dj < d2 || (dj == d2 && oj < o)) ? 1 : 0;
            }
            if (rank < K_NBR) nbr[m * K_NBR + rank] = o;
        }
        if (lane == 0) ncnt[m] = K_NBR;
    }
}

// ---------- PointConv MLP + masked max-pool (fp32, one block / centroid) ----------

__global__ __launch_bounds__(256) void mlp_kernel(
        const float* __restrict__ x, const float* __restrict__ pos,
        const float* __restrict__ W1, const float* __restrict__ b1,
        const float* __restrict__ W2, const float* __restrict__ b2,
        const int* __restrict__ sel, const int* __restrict__ nbr,
        const int* __restrict__ ncnt, float* __restrict__ out) {
    __shared__ __align__(16) float feat[64][68];   // 67 used + pad
    __shared__ __align__(16) float h[64][H_MID];
    __shared__ float part[2][H_MID];

    const int m = blockIdx.x;
    const int tid = threadIdx.x;
    const int cnt = ncnt[m];
    const int s = sel[m];
    float cx = pos[3*s], cy = pos[3*s+1], cz = pos[3*s+2];

    for (int i = tid; i < 64 * 68; i += 256) ((float*)feat)[i] = 0.0f;
    __syncthreads();

    for (int i = tid; i < cnt * F_IN; i += 256) {
        int k = i >> 6, f = i & 63;
        int j = nbr[m * K_NBR + k];
        feat[k][f] = x[(size_t)j * F_IN + f];
    }
    if (tid < 64 && tid < cnt) {
        int j = nbr[m * K_NBR + tid];
        feat[tid][64] = pos[3*j]     - cx;
        feat[tid][65] = pos[3*j + 1] - cy;
        feat[tid][66] = pos[3*j + 2] - cz;
    }
    __syncthreads();

    const int c = tid & 127;
    const int half = tid >> 7;

    for (int k = half; k < 64; k += 2) {
        float acc = b1[c];
        const float4* fr = (const float4*)&feat[k][0];
#pragma unroll
        for (int f4 = 0; f4 < 16; ++f4) {
            float4 fv = fr[f4];
            int fb = f4 * 4;
            acc = fmaf(fv.x, W1[(fb    ) * H_MID + c], acc);
            acc = fmaf(fv.y, W1[(fb + 1) * H_MID + c], acc);
            acc = fmaf(fv.z, W1[(fb + 2) * H_MID + c], acc);
            acc = fmaf(fv.w, W1[(fb + 3) * H_MID + c], acc);
        }
        acc = fmaf(feat[k][64], W1[64 * H_MID + c], acc);
        acc = fmaf(feat[k][65], W1[65 * H_MID + c], acc);
        acc = fmaf(feat[k][66], W1[66 * H_MID + c], acc);
        h[k][c] = fmaxf(acc, 0.0f);
    }
    __syncthreads();

    float best = -INFINITY;
    for (int k = half; k < cnt; k += 2) {
        float acc = 0.0f;
        const float4* hr = (const float4*)&h[k][0];
#pragma unroll
        for (int q = 0; q < 32; ++q) {
            float4 hv = hr[q];
            int hb = q * 4;
            acc = fmaf(hv.x, W2[(hb    ) * C_OUT + c], acc);
            acc = fmaf(hv.y, W2[(hb + 1) * C_OUT + c], acc);
            acc = fmaf(hv.z, W2[(hb + 2) * C_OUT + c], acc);
            acc = fmaf(hv.w, W2[(hb + 3) * C_OUT + c], acc);
        }
        best = fmaxf(best, acc);
    }
    part[half][c] = best;
    __syncthreads();
    if (tid < 128) {
        out[(size_t)m * C_OUT + tid] = fmaxf(part[0][tid], part[1][tid]) + b2[tid];
    }
}

// ---------- outputs 2 & 3 ----------

__global__ void tail_kernel(const float* __restrict__ pos, const int* __restrict__ sel,
                            float* __restrict__ out_selpos, float* __restrict__ out_batch) {
    int i = blockIdx.x * blockDim.x + threadIdx.x;
    if (i < M_SEL) {
        int s = sel[i];
        out_selpos[3*i]     = pos[3*s];
        out_selpos[3*i + 1] = pos[3*s + 1];
        out_selpos[3*i + 2] = pos[3*s + 2];
        out_batch[i] = 0.0f;
    }
}

// ---------- launch ----------

extern "C" void kernel_launch(void* const* d_in, const int* in_sizes, int n_in,
                              void* d_out, int out_size, void* d_ws, size_t ws_size,
                              hipStream_t stream) {
    const float* x   = (const float*)d_in[0];
    const float* pos = (const float*)d_in[1];
    // d_in[2] = batch (int64, all zeros) — unused
    const float* W1 = (const float*)d_in[3];
    const float* b1 = (const float*)d_in[4];
    const float* W2 = (const float*)d_in[5];
    const float* b2 = (const float*)d_in[6];

    float* out        = (float*)d_out;
    float* out_selpos = out + (size_t)M_SEL * C_OUT;
    float* out_batch  = out_selpos + (size_t)M_SEL * 3;

    char* ws = (char*)d_ws;
    size_t off = 0;
    auto alloc = [&](size_t bytes) -> void* {
        void* p = ws + off;
        off = (off + bytes + 255) & ~(size_t)255;
        return p;
    };
    int*    cnt    = (int*)alloc(NCELL * 4);
    int*    cstart = (int*)alloc((NCELL + 1) * 4);
    int*    cfill  = (int*)alloc(NCELL * 4);
    float4* pq     = (float4*)alloc((size_t)N_PTS * 16);
    int*    sel    = (int*)alloc(M_SEL * 4);
    int*    nbr    = (int*)alloc((size_t)M_SEL * K_NBR * 4);
    int*    ncnt   = (int*)alloc(M_SEL * 4);
    (void)ws_size; (void)in_sizes; (void)n_in; (void)out_size;

    (void)hipMemsetAsync(cnt, 0, NCELL * 4, stream);
    bin_count_kernel<<<N_PTS / 256, 256, 0, stream>>>(pos, cnt);
    scan_kernel<<<1, NCELL, 0, stream>>>(cnt, cstart, cfill);
    scatter_kernel<<<N_PTS / 256, 256, 0, stream>>>(pos, cfill, pq);
    fps_kernel<<<1, NT, 0, stream>>>(pq, cstart, pos, sel);
    ballq_kernel<<<M_SEL / 4, 256, 0, stream>>>(pos, pq, cstart, sel, nbr, ncnt);
    mlp_kernel<<<M_SEL, 256, 0, stream>>>(x, pos, W1, b1, W2, b2, sel, nbr, ncnt, out);
    tail_kernel<<<(M_SEL + 255) / 256, 256, 0, stream>>>(pos, sel, out_selpos, out_batch);
}

// Round 7
// 18194.470 us; speedup vs baseline: 1.7677x; 1.7677x over previous
//
#include <hip/hip_runtime.h>
#include <math.h>

#define N_PTS 32768
#define M_SEL 8192
#define K_NBR 64
#define F_IN  64
#define H_MID 128
#define C_OUT 128
#define NCELL 512   // 8x8x8 grid
#define CAP   192   // per-centroid candidate cap
#define NW    4     // waves in fps block
#define NT    (NW * 64)

// ---------- helpers ----------

__device__ __forceinline__ int clamp8(int v) { return v < 0 ? 0 : (v > 7 ? 7 : v); }

__device__ __forceinline__ int cell_of(float px, float py, float pz) {
    int ix = clamp8((int)(px * 8.0f));
    int iy = clamp8((int)(py * 8.0f));
    int iz = clamp8((int)(pz * 8.0f));
    return (iz * 8 + iy) * 8 + ix;
}

// Bit-exact replica of numpy: ((dx*dx + dy*dy) + dz*dz), rn, no fma.
__device__ __forceinline__ float d2_exact(float ax, float ay, float az,
                                          float bx, float by, float bz) {
#pragma clang fp contract(off)
    float dx = ax - bx, dy = ay - by, dz = az - bz;
    return (dx * dx + dy * dy) + dz * dz;
}

__device__ __forceinline__ unsigned long long umax64(unsigned long long a,
                                                     unsigned long long b) {
    return a > b ? a : b;
}

// ---------- binning ----------

__global__ void bin_count_kernel(const float* __restrict__ pos, int* __restrict__ cnt) {
    int i = blockIdx.x * blockDim.x + threadIdx.x;
    if (i < N_PTS) {
        atomicAdd(&cnt[cell_of(pos[3*i], pos[3*i+1], pos[3*i+2])], 1);
    }
}

__global__ void scan_kernel(const int* __restrict__ cnt, int* __restrict__ start,
                            int* __restrict__ fill) {
    __shared__ int s[NCELL];
    int t = threadIdx.x;
    int v = cnt[t];
    s[t] = v;
    __syncthreads();
    for (int off = 1; off < NCELL; off <<= 1) {
        int add = (t >= off) ? s[t - off] : 0;
        __syncthreads();
        s[t] += add;
        __syncthreads();
    }
    int ex = s[t] - v;           // exclusive scan
    start[t] = ex;
    fill[t]  = ex;
    if (t == NCELL - 1) start[NCELL] = s[t];
}

// pq[slot] = (x, y, z, orig_index_as_float_bits) — one dwordx4 per point
__global__ void scatter_kernel(const float* __restrict__ pos, int* __restrict__ fill,
                               float4* __restrict__ pq) {
    int i = blockIdx.x * blockDim.x + threadIdx.x;
    if (i < N_PTS) {
        float px = pos[3*i], py = pos[3*i+1], pz = pos[3*i+2];
        int c = cell_of(px, py, pz);
        int slot = atomicAdd(&fill[c], 1);
        pq[slot] = make_float4(px, py, pz, __int_as_float(i));
    }
}

// ---------- FPS ----------
// 256 threads (4 waves). mind[] LDS-resident. Flagged cells compacted into a
// shared list during flag computation (rank from cumulative ballots = list
// index; writer wave = rank & 3; no atomics). B-phase: whole-wave rounds per
// cell with a 2-deep software pipeline — the next assigned cell's points and
// mind values are prefetched into registers while the current cell computes.
// Per-cell max via 4 u64 sub-slots (ds_max_u64). Replicated argmax via 8-slot
// LDS atomic tree. 2 barriers/iteration.

__global__ __launch_bounds__(NT) void fps_kernel(
        const float4* __restrict__ pq, const int* __restrict__ cstart,
        const float* __restrict__ pos, int* __restrict__ sel) {
    __shared__ float s_mind[N_PTS];                       // 128 KB
    __shared__ unsigned long long s_sub[NCELL][4];        // 16 KB
    __shared__ unsigned long long s_best[NCELL];          // 4 KB
    __shared__ unsigned long long s_redw[NW][8];          // 256 B
    __shared__ int s_cs[NCELL + 1];
    __shared__ unsigned short s_flist[NCELL];             // 1 KB

    const int tid  = threadIdx.x;
    const int lane = tid & 63;
    const int wid  = tid >> 6;
    const unsigned long long lmask_lt = (1ULL << lane) - 1ULL;

    for (int i = tid; i < N_PTS; i += NT) s_mind[i] = INFINITY;
    for (int i = tid; i < NCELL + 1; i += NT) s_cs[i] = cstart[i];
    for (int c = tid; c < NCELL; c += NT)
        s_best[c] = (cstart[c + 1] > cstart[c])
                    ? ((0x7F800000ULL << 32) | 0xFFFFFFFFULL) : 0ULL;
    if (tid == 0) sel[0] = 0;
    __syncthreads();

    // per-lane cell geometry (cells lane + 64k)
    float lox[8], loy[8], loz[8];
    #pragma unroll
    for (int k = 0; k < 8; ++k) {
        const int c = lane + (k << 6);
        lox[k] = (float)(c & 7)        * 0.125f;
        loy[k] = (float)((c >> 3) & 7) * 0.125f;
        loz[k] = (float)(c >> 6)       * 0.125f;
    }

    unsigned long long vb[8];     // current per-cell best (replicated view)
    unsigned long long fm[8];     // flag masks (identical in all waves)
    int nf = 0;                   // flagged count (replicated)
    float px = pos[0], py = pos[1], pz = pos[2];

    #pragma unroll
    for (int k = 0; k < 8; ++k) vb[k] = s_best[lane + (k << 6)];

    auto flag_assign = [&]() {
        unsigned int cum = 0;
        #pragma unroll
        for (int k = 0; k < 8; ++k) {
            const float cm = __uint_as_float((unsigned int)(vb[k] >> 32));
            float dx = fmaxf(fmaxf(lox[k] - px, px - (lox[k] + 0.125f)), 0.0f);
            float dy = fmaxf(fmaxf(loy[k] - py, py - (loy[k] + 0.125f)), 0.0f);
            float dz = fmaxf(fmaxf(loz[k] - pz, pz - (loz[k] + 0.125f)), 0.0f);
            float lb2 = dx * dx + dy * dy + dz * dz;
            bool fl = (lb2 * 0.999f < cm);               // conservative skip bound
            unsigned long long b = __ballot(fl);
            fm[k] = b;
            unsigned int rank = cum + (unsigned int)__popcll(b & lmask_lt);
            if (fl && (rank & (NW - 1)) == (unsigned)wid)
                s_flist[rank] = (unsigned short)(lane + (k << 6));
            cum += (unsigned int)__popcll(b);
        }
        nf = (int)cum;
    };
    flag_assign();
    __syncthreads();

    for (int m = 1; m < M_SEL; ++m) {
        // ---- B: process assigned cells (stride-NW over shared list), with a
        //      2-deep pipeline: cell i+NW's data prefetched during cell i ----
        if (lane < 8) s_redw[wid][lane] = 0ULL;          // reset own reduce slots

        int i = wid;
        int cA = -1, csA = 0, ceA = 0;
        float4 qA1, qA2; float mdA1 = 0.0f, mdA2 = 0.0f;
        bool hA1 = false, hA2 = false;
        if (i < nf) {
            cA = s_flist[i];
            csA = s_cs[cA]; ceA = s_cs[cA + 1];
            int j1 = csA + lane, j2 = csA + lane + 64;
            hA1 = (j1 < ceA); hA2 = (j2 < ceA);
            if (hA1) { qA1 = pq[j1]; mdA1 = s_mind[j1]; }
            if (hA2) { qA2 = pq[j2]; mdA2 = s_mind[j2]; }
        }
        while (cA >= 0) {
            // prefetch cell i+NW
            const int i2 = i + NW;
            int cB = -1, csB = 0, ceB = 0;
            float4 qB1, qB2; float mdB1 = 0.0f, mdB2 = 0.0f;
            bool hB1 = false, hB2 = false;
            if (i2 < nf) {
                cB = s_flist[i2];
                csB = s_cs[cB]; ceB = s_cs[cB + 1];
                int j1 = csB + lane, j2 = csB + lane + 64;
                hB1 = (j1 < ceB); hB2 = (j2 < ceB);
                if (hB1) { qB1 = pq[j1]; mdB1 = s_mind[j1]; }
                if (hB2) { qB2 = pq[j2]; mdB2 = s_mind[j2]; }
            }
            // process cell A from registers
            if (lane < 4) s_sub[cA][lane] = 0ULL;        // in-order before atomics
            if (hA1) {
                const float d2 = d2_exact(qA1.x, qA1.y, qA1.z, px, py, pz);
                const float nv = d2 < mdA1 ? d2 : mdA1;
                s_mind[csA + lane] = nv;
                const unsigned long long pk =
                    ((unsigned long long)__float_as_uint(nv) << 32)
                    | (unsigned long long)(~(unsigned int)__float_as_int(qA1.w));
                atomicMax(&s_sub[cA][lane >> 4], pk);
            }
            if (hA2) {
                const float d2 = d2_exact(qA2.x, qA2.y, qA2.z, px, py, pz);
                const float nv = d2 < mdA2 ? d2 : mdA2;
                s_mind[csA + lane + 64] = nv;
                const unsigned long long pk =
                    ((unsigned long long)__float_as_uint(nv) << 32)
                    | (unsigned long long)(~(unsigned int)__float_as_int(qA2.w));
                atomicMax(&s_sub[cA][lane >> 4], pk);
            }
            // rare tail: cells with more than 128 points
            for (int j = csA + lane + 128; j < ceA; j += 64) {
                const float4 q  = pq[j];
                const float d2  = d2_exact(q.x, q.y, q.z, px, py, pz);
                const float old = s_mind[j];
                const float nv  = d2 < old ? d2 : old;
                s_mind[j] = nv;
                const unsigned long long pk =
                    ((unsigned long long)__float_as_uint(nv) << 32)
                    | (unsigned long long)(~(unsigned int)__float_as_int(q.w));
                atomicMax(&s_sub[cA][lane >> 4], pk);
            }
            // rotate pipeline
            i = i2; cA = cB; csA = csB; ceA = ceB;
            qA1 = qB1; qA2 = qB2; mdA1 = mdB1; mdA2 = mdB2; hA1 = hB1; hA2 = hB2;
        }
        __syncthreads();

        // ---- D: consolidate flagged cells, replicated argmax over 512 ----
        unsigned long long best = 0ULL;
        #pragma unroll
        for (int k = 0; k < 8; ++k) {
            const int c = lane + (k << 6);
            unsigned long long v;
            if ((fm[k] >> lane) & 1ULL) {
                const unsigned long long v0 = s_sub[c][0], v1 = s_sub[c][1];
                const unsigned long long v2 = s_sub[c][2], v3 = s_sub[c][3];
                v = umax64(umax64(v0, v1), umax64(v2, v3));
                if (wid == 0) s_best[c] = v;             // persist for later iters
            } else {
                v = s_best[c];
            }
            vb[k] = v;
            best = umax64(best, v);
        }
        atomicMax(&s_redw[wid][lane & 7], best);         // intra-wave, in-order
        #pragma unroll
        for (int i2 = 0; i2 < 8; ++i2) best = umax64(best, s_redw[wid][i2]);

        const unsigned int orig = ~(unsigned int)best;
        if (tid == 0) sel[m] = (int)orig;
        px = pos[3 * orig]; py = pos[3 * orig + 1]; pz = pos[3 * orig + 2];

        // ---- F: flags + shared list for next iteration ----
        flag_assign();
        __syncthreads();     // D/F reads done before next B's writes
    }
}

// ---------- ball query: up-to-64 nearest in-radius (one wave / centroid) ----------

__global__ __launch_bounds__(256) void ballq_kernel(
        const float* __restrict__ pos,
        const float4* __restrict__ pq,
        const int* __restrict__ cstart, const int* __restrict__ sel,
        int* __restrict__ nbr, int* __restrict__ ncnt) {
    __shared__ float s_d2[4][CAP];
    __shared__ int   s_o[4][CAP];
    __shared__ int   s_cnt[4];

    const int wid  = threadIdx.x >> 6;
    const int lane = threadIdx.x & 63;
    const int m = blockIdx.x * 4 + wid;

    if (lane == 0) s_cnt[wid] = 0;
    __syncthreads();

    int sidx = sel[m];
    float cx = pos[3*sidx], cy = pos[3*sidx+1], cz = pos[3*sidx+2];
    int ix = clamp8((int)(cx * 8.0f));
    int iy = clamp8((int)(cy * 8.0f));
    int iz = clamp8((int)(cz * 8.0f));
    const float r2 = (float)(0.08 * 0.08);

    for (int dz = -1; dz <= 1; ++dz) {
        int z = iz + dz; if (z < 0 || z > 7) continue;
        for (int dy = -1; dy <= 1; ++dy) {
            int y = iy + dy; if (y < 0 || y > 7) continue;
            for (int dx = -1; dx <= 1; ++dx) {
                int xq = ix + dx; if (xq < 0 || xq > 7) continue;
                int c = (z * 8 + y) * 8 + xq;
                int cs = cstart[c], ce = cstart[c + 1];
                for (int j = cs + lane; j < ce; j += 64) {
                    float4 q = pq[j];
                    float d2 = d2_exact(cx, cy, cz, q.x, q.y, q.z);
                    if (d2 <= r2) {
                        int slot = atomicAdd(&s_cnt[wid], 1);
                        if (slot < CAP) { s_d2[wid][slot] = d2; s_o[wid][slot] = __float_as_int(q.w); }
                    }
                }
            }
        }
    }
    __syncthreads();

    int cnt = s_cnt[wid];
    if (cnt > CAP) cnt = CAP;
    if (cnt <= K_NBR) {
        if (lane < cnt) nbr[m * K_NBR + lane] = s_o[wid][lane];
        if (lane == 0) ncnt[m] = cnt;
    } else {
        // exact (d2, orig-index) lexicographic rank -> keep 64 nearest (matches top_k)
        for (int i = lane; i < cnt; i += 64) {
            float d2 = s_d2[wid][i];
            int   o  = s_o[wid][i];
            int rank = 0;
            for (int j = 0; j < cnt; ++j) {
                float dj = s_d2[wid][j];
                int   oj = s_o[wid][j];
                rank += (dj < d2 || (dj == d2 && oj < o)) ? 1 : 0;
            }
            if (rank < K_NBR) nbr[m * K_NBR + rank] = o;
        }
        if (lane == 0) ncnt[m] = K_NBR;
    }
}

// ---------- PointConv MLP + masked max-pool (fp32, one block / centroid) ----------

__global__ __launch_bounds__(256) void mlp_kernel(
        const float* __restrict__ x, const float* __restrict__ pos,
        const float* __restrict__ W1, const float* __restrict__ b1,
        const float* __restrict__ W2, const float* __restrict__ b2,
        const int* __restrict__ sel, const int* __restrict__ nbr,
        const int* __restrict__ ncnt, float* __restrict__ out) {
    __shared__ __align__(16) float feat[64][68];   // 67 used + pad
    __shared__ __align__(16) float h[64][H_MID];
    __shared__ float part[2][H_MID];

    const int m = blockIdx.x;
    const int tid = threadIdx.x;
    const int cnt = ncnt[m];
    const int s = sel[m];
    float cx = pos[3*s], cy = pos[3*s+1], cz = pos[3*s+2];

    for (int i = tid; i < 64 * 68; i += 256) ((float*)feat)[i] = 0.0f;
    __syncthreads();

    for (int i = tid; i < cnt * F_IN; i += 256) {
        int k = i >> 6, f = i & 63;
        int j = nbr[m * K_NBR + k];
        feat[k][f] = x[(size_t)j * F_IN + f];
    }
    if (tid < 64 && tid < cnt) {
        int j = nbr[m * K_NBR + tid];
        feat[tid][64] = pos[3*j]     - cx;
        feat[tid][65] = pos[3*j + 1] - cy;
        feat[tid][66] = pos[3*j + 2] - cz;
    }
    __syncthreads();

    const int c = tid & 127;
    const int half = tid >> 7;

    for (int k = half; k < 64; k += 2) {
        float acc = b1[c];
        const float4* fr = (const float4*)&feat[k][0];
#pragma unroll
        for (int f4 = 0; f4 < 16; ++f4) {
            float4 fv = fr[f4];
            int fb = f4 * 4;
            acc = fmaf(fv.x, W1[(fb    ) * H_MID + c], acc);
            acc = fmaf(fv.y, W1[(fb + 1) * H_MID + c], acc);
            acc = fmaf(fv.z, W1[(fb + 2) * H_MID + c], acc);
            acc = fmaf(fv.w, W1[(fb + 3) * H_MID + c], acc);
        }
        acc = fmaf(feat[k][64], W1[64 * H_MID + c], acc);
        acc = fmaf(feat[k][65], W1[65 * H_MID + c], acc);
        acc = fmaf(feat[k][66], W1[66 * H_MID + c], acc);
        h[k][c] = fmaxf(acc, 0.0f);
    }
    __syncthreads();

    float best = -INFINITY;
    for (int k = half; k < cnt; k += 2) {
        float acc = 0.0f;
        const float4* hr = (const float4*)&h[k][0];
#pragma unroll
        for (int q = 0; q < 32; ++q) {
            float4 hv = hr[q];
            int hb = q * 4;
            acc = fmaf(hv.x, W2[(hb    ) * C_OUT + c], acc);
            acc = fmaf(hv.y, W2[(hb + 1) * C_OUT + c], acc);
            acc = fmaf(hv.z, W2[(hb + 2) * C_OUT + c], acc);
            acc = fmaf(hv.w, W2[(hb + 3) * C_OUT + c], acc);
        }
        best = fmaxf(best, acc);
    }
    part[half][c] = best;
    __syncthreads();
    if (tid < 128) {
        out[(size_t)m * C_OUT + tid] = fmaxf(part[0][tid], part[1][tid]) + b2[tid];
    }
}

// ---------- outputs 2 & 3 ----------

__global__ void tail_kernel(const float* __restrict__ pos, const int* __restrict__ sel,
                            float* __restrict__ out_selpos, float* __restrict__ out_batch) {
    int i = blockIdx.x * blockDim.x + threadIdx.x;
    if (i < M_SEL) {
        int s = sel[i];
        out_selpos[3*i]     = pos[3*s];
        out_selpos[3*i + 1] = pos[3*s + 1];
        out_selpos[3*i + 2] = pos[3*s + 2];
        out_batch[i] = 0.0f;
    }
}

// ---------- launch ----------

extern "C" void kernel_launch(void* const* d_in, const int* in_sizes, int n_in,
                              void* d_out, int out_size, void* d_ws, size_t ws_size,
                              hipStream_t stream) {
    const float* x   = (const float*)d_in[0];
    const float* pos = (const float*)d_in[1];
    // d_in[2] = batch (int64, all zeros) — unused
    const float* W1 = (const float*)d_in[3];
    const float* b1 = (const float*)d_in[4];
    const float* W2 = (const float*)d_in[5];
    const float* b2 = (const float*)d_in[6];

    float* out        = (float*)d_out;
    float* out_selpos = out + (size_t)M_SEL * C_OUT;
    float* out_batch  = out_selpos + (size_t)M_SEL * 3;

    char* ws = (char*)d_ws;
    size_t off = 0;
    auto alloc = [&](size_t bytes) -> void* {
        void* p = ws + off;
        off = (off + bytes + 255) & ~(size_t)255;
        return p;
    };
    int*    cnt    = (int*)alloc(NCELL * 4);
    int*    cstart = (int*)alloc((NCELL + 1) * 4);
    int*    cfill  = (int*)alloc(NCELL * 4);
    float4* pq     = (float4*)alloc((size_t)N_PTS * 16);
    int*    sel    = (int*)alloc(M_SEL * 4);
    int*    nbr    = (int*)alloc((size_t)M_SEL * K_NBR * 4);
    int*    ncnt   = (int*)alloc(M_SEL * 4);
    (void)ws_size; (void)in_sizes; (void)n_in; (void)out_size;

    (void)hipMemsetAsync(cnt, 0, NCELL * 4, stream);
    bin_count_kernel<<<N_PTS / 256, 256, 0, stream>>>(pos, cnt);
    scan_kernel<<<1, NCELL, 0, stream>>>(cnt, cstart, cfill);
    scatter_kernel<<<N_PTS / 256, 256, 0, stream>>>(pos, cfill, pq);
    fps_kernel<<<1, NT, 0, stream>>>(pq, cstart, pos, sel);
    ballq_kernel<<<M_SEL / 4, 256, 0, stream>>>(pos, pq, cstart, sel, nbr, ncnt);
    mlp_kernel<<<M_SEL, 256, 0, stream>>>(x, pos, W1, b1, W2, b2, sel, nbr, ncnt, out);
    tail_kernel<<<(M_SEL + 255) / 256, 256, 0, stream>>>(pos, sel, out_selpos, out_batch);
}

// Round 8
// 17494.540 us; speedup vs baseline: 1.8384x; 1.0400x over previous
//
#include <hip/hip_runtime.h>
#include <math.h>

#define N_PTS 32768
#define M_SEL 8192
#define K_NBR 64
#define F_IN  64
#define H_MID 128
#define C_OUT 128
#define NCELL 512   // 8x8x8 grid
#define CAP   192   // per-centroid candidate cap
#define NW    4     // waves in fps block
#define NT    (NW * 64)

// ---------- helpers ----------

__device__ __forceinline__ int clamp8(int v) { return v < 0 ? 0 : (v > 7 ? 7 : v); }

__device__ __forceinline__ int cell_of(float px, float py, float pz) {
    int ix = clamp8((int)(px * 8.0f));
    int iy = clamp8((int)(py * 8.0f));
    int iz = clamp8((int)(pz * 8.0f));
    return (iz * 8 + iy) * 8 + ix;
}

// Bit-exact replica of numpy: ((dx*dx + dy*dy) + dz*dz), rn, no fma.
__device__ __forceinline__ float d2_exact(float ax, float ay, float az,
                                          float bx, float by, float bz) {
#pragma clang fp contract(off)
    float dx = ax - bx, dy = ay - by, dz = az - bz;
    return (dx * dx + dy * dy) + dz * dz;
}

__device__ __forceinline__ unsigned long long umax64(unsigned long long a,
                                                     unsigned long long b) {
    return a > b ? a : b;
}

// pack: [63:32] mind_bits (nonneg float -> uint order), [29:15] orig^0x7FFF,
//       [14:0] slot. Lex order = (mind, -orig); slot never decides (orig unique).
__device__ __forceinline__ unsigned long long make_pk(float nv, unsigned int o,
                                                      unsigned int slot) {
    return ((unsigned long long)__float_as_uint(nv) << 32)
         | ((unsigned long long)((o ^ 0x7FFFu) & 0x7FFFu) << 15)
         | (unsigned long long)slot;
}

// ---------- binning ----------

__global__ void bin_count_kernel(const float* __restrict__ pos, int* __restrict__ cnt) {
    int i = blockIdx.x * blockDim.x + threadIdx.x;
    if (i < N_PTS) {
        atomicAdd(&cnt[cell_of(pos[3*i], pos[3*i+1], pos[3*i+2])], 1);
    }
}

__global__ void scan_kernel(const int* __restrict__ cnt, int* __restrict__ start,
                            int* __restrict__ fill) {
    __shared__ int s[NCELL];
    int t = threadIdx.x;
    int v = cnt[t];
    s[t] = v;
    __syncthreads();
    for (int off = 1; off < NCELL; off <<= 1) {
        int add = (t >= off) ? s[t - off] : 0;
        __syncthreads();
        s[t] += add;
        __syncthreads();
    }
    int ex = s[t] - v;           // exclusive scan
    start[t] = ex;
    fill[t]  = ex;
    if (t == NCELL - 1) start[NCELL] = s[t];
}

// pq[slot] = (x, y, z, orig_index_as_float_bits) — one dwordx4 per point
__global__ void scatter_kernel(const float* __restrict__ pos, int* __restrict__ fill,
                               float4* __restrict__ pq) {
    int i = blockIdx.x * blockDim.x + threadIdx.x;
    if (i < N_PTS) {
        float px = pos[3*i], py = pos[3*i+1], pz = pos[3*i+2];
        int c = cell_of(px, py, pz);
        int slot = atomicAdd(&fill[c], 1);
        pq[slot] = make_float4(px, py, pz, __int_as_float(i));
    }
}

// ---------- FPS ----------
// 256 threads (4 waves). mind[] LDS-resident. Cell descriptors (cs|len|c)
// packed in per-lane registers; F writes them straight into the shared flag
// list, so B's decode is a single LDS read. vb[] registers hold per-cell best
// across iterations (no s_best array). Winner's coords come from pq[slot]
// (slot packed in the reduction key). 2 barriers/iteration.

__global__ __launch_bounds__(NT) void fps_kernel(
        const float4* __restrict__ pq, const int* __restrict__ cstart,
        const float* __restrict__ pos, int* __restrict__ sel) {
    __shared__ float s_mind[N_PTS];                       // 128 KB
    __shared__ unsigned long long s_sub[NCELL][4];        // 16 KB
    __shared__ unsigned long long s_redw[NW][8];          // 256 B
    __shared__ int s_cs[NCELL + 1];                       // ~2 KB (len==255 fallback)
    __shared__ unsigned int s_flist[NCELL];               // 2 KB

    const int tid  = threadIdx.x;
    const int lane = tid & 63;
    const int wid  = tid >> 6;
    const unsigned long long lmask_lt = (1ULL << lane) - 1ULL;

    for (int i = tid; i < N_PTS; i += NT) s_mind[i] = INFINITY;
    for (int i = tid; i < NCELL + 1; i += NT) s_cs[i] = cstart[i];
    if (tid == 0) sel[0] = 0;
    __syncthreads();

    // per-lane cell geometry + packed descriptors (cells lane + 64k)
    float lox[8], loy[8], loz[8];
    unsigned int ent[8];
    unsigned long long vb[8];     // per-cell best (replicated registers)
    #pragma unroll
    for (int k = 0; k < 8; ++k) {
        const int c = lane + (k << 6);
        lox[k] = (float)(c & 7)        * 0.125f;
        loy[k] = (float)((c >> 3) & 7) * 0.125f;
        loz[k] = (float)(c >> 6)       * 0.125f;
        const int cs = s_cs[c], ce = s_cs[c + 1];
        int len = ce - cs; if (len > 255) len = 255;
        ent[k] = (unsigned int)cs | ((unsigned int)len << 15)
               | ((unsigned int)c << 23);
        // +inf sentinel => every nonempty cell flagged on iteration 1
        vb[k] = (ce > cs) ? ((0x7F800000ULL << 32) | 0x3FFFFFFFULL) : 0ULL;
    }

    unsigned long long fm[8];     // flag masks (identical in all waves)
    int nf = 0;                   // flagged count (replicated)
    float px = pos[0], py = pos[1], pz = pos[2];

    auto flag_assign = [&]() {
        unsigned int cum = 0;
        #pragma unroll
        for (int k = 0; k < 8; ++k) {
            const float cm = __uint_as_float((unsigned int)(vb[k] >> 32));
            float dx = fmaxf(fmaxf(lox[k] - px, px - (lox[k] + 0.125f)), 0.0f);
            float dy = fmaxf(fmaxf(loy[k] - py, py - (loy[k] + 0.125f)), 0.0f);
            float dz = fmaxf(fmaxf(loz[k] - pz, pz - (loz[k] + 0.125f)), 0.0f);
            float lb2 = dx * dx + dy * dy + dz * dz;
            bool fl = (lb2 * 0.999f < cm);               // conservative skip bound
            unsigned long long b = __ballot(fl);
            fm[k] = b;
            unsigned int rank = cum + (unsigned int)__popcll(b & lmask_lt);
            if (fl && (rank & (NW - 1)) == (unsigned)wid)
                s_flist[rank] = ent[k];
            cum += (unsigned int)__popcll(b);
        }
        nf = (int)cum;
    };
    flag_assign();
    __syncthreads();

    for (int m = 1; m < M_SEL; ++m) {
        // ---- B: process assigned cells (stride-NW over shared list), with a
        //      depth-1 pipeline; descriptor decode is a single LDS read ----
        if (lane < 8) s_redw[wid][lane] = 0ULL;          // reset own reduce slots

        int i = wid;
        int vA = 0, cA = 0, csA = 0, ceA = 0;
        float4 qA1, qA2; float mdA1 = 0.0f, mdA2 = 0.0f;
        bool hA1 = false, hA2 = false;
        if (i < nf) {
            vA = 1;
            const unsigned int e = s_flist[i];
            cA = (int)(e >> 23); csA = (int)(e & 0x7FFFu);
            const int len = (int)((e >> 15) & 0xFFu);
            ceA = csA + len; if (len == 255) ceA = s_cs[cA + 1];
            const int j1 = csA + lane, j2 = j1 + 64;
            hA1 = (j1 < ceA); hA2 = (j2 < ceA);
            if (hA1) { qA1 = pq[j1]; mdA1 = s_mind[j1]; }
            if (hA2) { qA2 = pq[j2]; mdA2 = s_mind[j2]; }
        }
        while (vA) {
            // prefetch cell i+NW
            const int i2 = i + NW;
            int vB = 0, cB = 0, csB = 0, ceB = 0;
            float4 qB1, qB2; float mdB1 = 0.0f, mdB2 = 0.0f;
            bool hB1 = false, hB2 = false;
            if (i2 < nf) {
                vB = 1;
                const unsigned int e = s_flist[i2];
                cB = (int)(e >> 23); csB = (int)(e & 0x7FFFu);
                const int len = (int)((e >> 15) & 0xFFu);
                ceB = csB + len; if (len == 255) ceB = s_cs[cB + 1];
                const int j1 = csB + lane, j2 = j1 + 64;
                hB1 = (j1 < ceB); hB2 = (j2 < ceB);
                if (hB1) { qB1 = pq[j1]; mdB1 = s_mind[j1]; }
                if (hB2) { qB2 = pq[j2]; mdB2 = s_mind[j2]; }
            }
            // process cell A from registers
            if (lane < 4) s_sub[cA][lane] = 0ULL;        // in-order before atomics
            if (hA1) {
                const unsigned int j = (unsigned int)(csA + lane);
                const float d2 = d2_exact(qA1.x, qA1.y, qA1.z, px, py, pz);
                const float nv = d2 < mdA1 ? d2 : mdA1;
                s_mind[j] = nv;
                atomicMax(&s_sub[cA][lane >> 4],
                          make_pk(nv, (unsigned int)__float_as_int(qA1.w), j));
            }
            if (hA2) {
                const unsigned int j = (unsigned int)(csA + lane + 64);
                const float d2 = d2_exact(qA2.x, qA2.y, qA2.z, px, py, pz);
                const float nv = d2 < mdA2 ? d2 : mdA2;
                s_mind[j] = nv;
                atomicMax(&s_sub[cA][lane >> 4],
                          make_pk(nv, (unsigned int)__float_as_int(qA2.w), j));
            }
            // rare tail: cells with more than 128 points
            for (int j = csA + lane + 128; j < ceA; j += 64) {
                const float4 q  = pq[j];
                const float d2  = d2_exact(q.x, q.y, q.z, px, py, pz);
                const float old = s_mind[j];
                const float nv  = d2 < old ? d2 : old;
                s_mind[j] = nv;
                atomicMax(&s_sub[cA][lane >> 4],
                          make_pk(nv, (unsigned int)__float_as_int(q.w),
                                  (unsigned int)j));
            }
            // rotate pipeline
            i = i2; vA = vB; cA = cB; csA = csB; ceA = ceB;
            qA1 = qB1; qA2 = qB2; mdA1 = mdB1; mdA2 = mdB2; hA1 = hB1; hA2 = hB2;
        }
        __syncthreads();

        // ---- D: consolidate flagged cells into vb regs, replicated argmax ----
        unsigned long long best = 0ULL;
        #pragma unroll
        for (int k = 0; k < 8; ++k) {
            if ((fm[k] >> lane) & 1ULL) {
                const int c = lane + (k << 6);
                const unsigned long long v0 = s_sub[c][0], v1 = s_sub[c][1];
                const unsigned long long v2 = s_sub[c][2], v3 = s_sub[c][3];
                vb[k] = umax64(umax64(v0, v1), umax64(v2, v3));
            }
            best = umax64(best, vb[k]);
        }
        atomicMax(&s_redw[wid][lane & 7], best);         // intra-wave, in-order
        #pragma unroll
        for (int i2 = 0; i2 < 8; ++i2) best = umax64(best, s_redw[wid][i2]);

        // ---- E: decode winner; coords from pq[slot] (hot) ----
        const unsigned int orig = (~(unsigned int)(best >> 15)) & 0x7FFFu;
        const unsigned int slot = (unsigned int)best & 0x7FFFu;
        if (tid == 0) sel[m] = (int)orig;
        const float4 qp = pq[slot];
        px = qp.x; py = qp.y; pz = qp.z;

        // ---- F: flags + shared list for next iteration ----
        flag_assign();
        __syncthreads();     // D/F reads done before next B's writes
    }
}

// ---------- ball query: up-to-64 nearest in-radius (one wave / centroid) ----------

__global__ __launch_bounds__(256) void ballq_kernel(
        const float* __restrict__ pos,
        const float4* __restrict__ pq,
        const int* __restrict__ cstart, const int* __restrict__ sel,
        int* __restrict__ nbr, int* __restrict__ ncnt) {
    __shared__ float s_d2[4][CAP];
    __shared__ int   s_o[4][CAP];
    __shared__ int   s_cnt[4];

    const int wid  = threadIdx.x >> 6;
    const int lane = threadIdx.x & 63;
    const int m = blockIdx.x * 4 + wid;

    if (lane == 0) s_cnt[wid] = 0;
    __syncthreads();

    int sidx = sel[m];
    float cx = pos[3*sidx], cy = pos[3*sidx+1], cz = pos[3*sidx+2];
    int ix = clamp8((int)(cx * 8.0f));
    int iy = clamp8((int)(cy * 8.0f));
    int iz = clamp8((int)(cz * 8.0f));
    const float r2 = (float)(0.08 * 0.08);

    for (int dz = -1; dz <= 1; ++dz) {
        int z = iz + dz; if (z < 0 || z > 7) continue;
        for (int dy = -1; dy <= 1; ++dy) {
            int y = iy + dy; if (y < 0 || y > 7) continue;
            for (int dx = -1; dx <= 1; ++dx) {
                int xq = ix + dx; if (xq < 0 || xq > 7) continue;
                int c = (z * 8 + y) * 8 + xq;
                int cs = cstart[c], ce = cstart[c + 1];
                for (int j = cs + lane; j < ce; j += 64) {
                    float4 q = pq[j];
                    float d2 = d2_exact(cx, cy, cz, q.x, q.y, q.z);
                    if (d2 <= r2) {
                        int slot = atomicAdd(&s_cnt[wid], 1);
                        if (slot < CAP) { s_d2[wid][slot] = d2; s_o[wid][slot] = __float_as_int(q.w); }
                    }
                }
            }
        }
    }
    __syncthreads();

    int cnt = s_cnt[wid];
    if (cnt > CAP) cnt = CAP;
    if (cnt <= K_NBR) {
        if (lane < cnt) nbr[m * K_NBR + lane] = s_o[wid][lane];
        if (lane == 0) ncnt[m] = cnt;
    } else {
        // exact (d2, orig-index) lexicographic rank -> keep 64 nearest (matches top_k)
        for (int i = lane; i < cnt; i += 64) {
            float d2 = s_d2[wid][i];
            int   o  = s_o[wid][i];
            int rank = 0;
            for (int j = 0; j < cnt; ++j) {
                float dj = s_d2[wid][j];
                int   oj = s_o[wid][j];
                rank += (dj < d2 || (dj == d2 && oj < o)) ? 1 : 0;
            }
            if (rank < K_NBR) nbr[m * K_NBR + rank] = o;
        }
        if (lane == 0) ncnt[m] = K_NBR;
    }
}

// ---------- PointConv MLP + masked max-pool (fp32, one block / centroid) ----------

__global__ __launch_bounds__(256) void mlp_kernel(
        const float* __restrict__ x, const float* __restrict__ pos,
        const float* __restrict__ W1, const float* __restrict__ b1,
        const float* __restrict__ W2, const float* __restrict__ b2,
        const int* __restrict__ sel, const int* __restrict__ nbr,
        const int* __restrict__ ncnt, float* __restrict__ out) {
    __shared__ __align__(16) float feat[64][68];   // 67 used + pad
    __shared__ __align__(16) float h[64][H_MID];
    __shared__ float part[2][H_MID];

    const int m = blockIdx.x;
    const int tid = threadIdx.x;
    const int cnt = ncnt[m];
    const int s = sel[m];
    float cx = pos[3*s], cy = pos[3*s+1], cz = pos[3*s+2];

    for (int i = tid; i < 64 * 68; i += 256) ((float*)feat)[i] = 0.0f;
    __syncthreads();

    for (int i = tid; i < cnt * F_IN; i += 256) {
        int k = i >> 6, f = i & 63;
        int j = nbr[m * K_NBR + k];
        feat[k][f] = x[(size_t)j * F_IN + f];
    }
    if (tid < 64 && tid < cnt) {
        int j = nbr[m * K_NBR + tid];
        feat[tid][64] = pos[3*j]     - cx;
        feat[tid][65] = pos[3*j + 1] - cy;
        feat[tid][66] = pos[3*j + 2] - cz;
    }
    __syncthreads();

    const int c = tid & 127;
    const int half = tid >> 7;

    for (int k = half; k < 64; k += 2) {
        float acc = b1[c];
        const float4* fr = (const float4*)&feat[k][0];
#pragma unroll
        for (int f4 = 0; f4 < 16; ++f4) {
            float4 fv = fr[f4];
            int fb = f4 * 4;
            acc = fmaf(fv.x, W1[(fb    ) * H_MID + c], acc);
            acc = fmaf(fv.y, W1[(fb + 1) * H_MID + c], acc);
            acc = fmaf(fv.z, W1[(fb + 2) * H_MID + c], acc);
            acc = fmaf(fv.w, W1[(fb + 3) * H_MID + c], acc);
        }
        acc = fmaf(feat[k][64], W1[64 * H_MID + c], acc);
        acc = fmaf(feat[k][65], W1[65 * H_MID + c], acc);
        acc = fmaf(feat[k][66], W1[66 * H_MID + c], acc);
        h[k][c] = fmaxf(acc, 0.0f);
    }
    __syncthreads();

    float best = -INFINITY;
    for (int k = half; k < cnt; k += 2) {
        float acc = 0.0f;
        const float4* hr = (const float4*)&h[k][0];
#pragma unroll
        for (int q = 0; q < 32; ++q) {
            float4 hv = hr[q];
            int hb = q * 4;
            acc = fmaf(hv.x, W2[(hb    ) * C_OUT + c], acc);
            acc = fmaf(hv.y, W2[(hb + 1) * C_OUT + c], acc);
            acc = fmaf(hv.z, W2[(hb + 2) * C_OUT + c], acc);
            acc = fmaf(hv.w, W2[(hb + 3) * C_OUT + c], acc);
        }
        best = fmaxf(best, acc);
    }
    part[half][c] = best;
    __syncthreads();
    if (tid < 128) {
        out[(size_t)m * C_OUT + tid] = fmaxf(part[0][tid], part[1][tid]) + b2[tid];
    }
}

// ---------- outputs 2 & 3 ----------

__global__ void tail_kernel(const float* __restrict__ pos, const int* __restrict__ sel,
                            float* __restrict__ out_selpos, float* __restrict__ out_batch) {
    int i = blockIdx.x * blockDim.x + threadIdx.x;
    if (i < M_SEL) {
        int s = sel[i];
        out_selpos[3*i]     = pos[3*s];
        out_selpos[3*i + 1] = pos[3*s + 1];
        out_selpos[3*i + 2] = pos[3*s + 2];
        out_batch[i] = 0.0f;
    }
}

// ---------- launch ----------

extern "C" void kernel_launch(void* const* d_in, const int* in_sizes, int n_in,
                              void* d_out, int out_size, void* d_ws, size_t ws_size,
                              hipStream_t stream) {
    const float* x   = (const float*)d_in[0];
    const float* pos = (const float*)d_in[1];
    // d_in[2] = batch (int64, all zeros) — unused
    const float* W1 = (const float*)d_in[3];
    const float* b1 = (const float*)d_in[4];
    const float* W2 = (const float*)d_in[5];
    const float* b2 = (const float*)d_in[6];

    float* out        = (float*)d_out;
    float* out_selpos = out + (size_t)M_SEL * C_OUT;
    float* out_batch  = out_selpos + (size_t)M_SEL * 3;

    char* ws = (char*)d_ws;
    size_t off = 0;
    auto alloc = [&](size_t bytes) -> void* {
        void* p = ws + off;
        off = (off + bytes + 255) & ~(size_t)255;
        return p;
    };
    int*    cnt    = (int*)alloc(NCELL * 4);
    int*    cstart = (int*)alloc((NCELL + 1) * 4);
    int*    cfill  = (int*)alloc(NCELL * 4);
    float4* pq     = (float4*)alloc((size_t)N_PTS * 16);
    int*    sel    = (int*)alloc(M_SEL * 4);
    int*    nbr    = (int*)alloc((size_t)M_SEL * K_NBR * 4);
    int*    ncnt   = (int*)alloc(M_SEL * 4);
    (void)ws_size; (void)in_sizes; (void)n_in; (void)out_size;

    (void)hipMemsetAsync(cnt, 0, NCELL * 4, stream);
    bin_count_kernel<<<N_PTS / 256, 256, 0, stream>>>(pos, cnt);
    scan_kernel<<<1, NCELL, 0, stream>>>(cnt, cstart, cfill);
    scatter_kernel<<<N_PTS / 256, 256, 0, stream>>>(pos, cfill, pq);
    fps_kernel<<<1, NT, 0, stream>>>(pq, cstart, pos, sel);
    ballq_kernel<<<M_SEL / 4, 256, 0, stream>>>(pos, pq, cstart, sel, nbr, ncnt);
    mlp_kernel<<<M_SEL, 256, 0, stream>>>(x, pos, W1, b1, W2, b2, sel, nbr, ncnt, out);
    tail_kernel<<<(M_SEL + 255) / 256, 256, 0, stream>>>(pos, sel, out_selpos, out_batch);
}

// Round 9
// 12999.722 us; speedup vs baseline: 2.4741x; 1.3458x over previous
//
#include <hip/hip_runtime.h>
#include <math.h>

#define N_PTS 32768
#define M_SEL 8192
#define K_NBR 64
#define F_IN  64
#define H_MID 128
#define C_OUT 128
#define NCELL 2048      // 16 x 16 x 8 grid, owner-swizzled cell index
#define CAP   192       // per-centroid candidate cap
#define NWF   16        // waves in fps block (one owner per wave)
#define NTF   (NWF * 64)

// ---------- helpers ----------

__device__ __forceinline__ int iclamp(int v, int hi) {
    return v < 0 ? 0 : (v > hi ? hi : v);
}

// owner-swizzled cell id: low 4 bits of (ix,iy,iz) interleaved -> owner wave,
// so any spatial neighborhood spreads across all 16 waves.
__device__ __forceinline__ int cell_idx(int ix, int iy, int iz) {
    int w    = (ix & 1) | ((iy & 1) << 1) | ((iz & 1) << 2) | (((ix >> 1) & 1) << 3);
    int rest = ((iz >> 1) * 8 + (iy >> 1)) * 4 + (ix >> 2);      // [0,128)
    return (w << 7) | rest;
}

__device__ __forceinline__ int cell_of(float px, float py, float pz) {
    int ix = iclamp((int)(px * 16.0f), 15);
    int iy = iclamp((int)(py * 16.0f), 15);
    int iz = iclamp((int)(pz * 8.0f), 7);
    return cell_idx(ix, iy, iz);
}

// Bit-exact replica of numpy: ((dx*dx + dy*dy) + dz*dz), rn, no fma.
__device__ __forceinline__ float d2_exact(float ax, float ay, float az,
                                          float bx, float by, float bz) {
#pragma clang fp contract(off)
    float dx = ax - bx, dy = ay - by, dz = az - bz;
    return (dx * dx + dy * dy) + dz * dz;
}

__device__ __forceinline__ unsigned long long umax64(unsigned long long a,
                                                     unsigned long long b) {
    return a > b ? a : b;
}

// pack: [63:32] mind_bits, [29:15] orig^0x7FFF, [14:0] slot.
// Lex order = (mind, -orig); slot never decides (orig unique).
__device__ __forceinline__ unsigned long long make_pk(float nv, unsigned int o,
                                                      unsigned int slot) {
    return ((unsigned long long)__float_as_uint(nv) << 32)
         | ((unsigned long long)((o ^ 0x7FFFu) & 0x7FFFu) << 15)
         | (unsigned long long)slot;
}

// ---------- binning ----------

__global__ void bin_count_kernel(const float* __restrict__ pos, int* __restrict__ cnt) {
    int i = blockIdx.x * blockDim.x + threadIdx.x;
    if (i < N_PTS) {
        atomicAdd(&cnt[cell_of(pos[3*i], pos[3*i+1], pos[3*i+2])], 1);
    }
}

// inclusive Hillis-Steele over 2048 with 1024 threads (2 elements each)
__global__ void scan_kernel(const int* __restrict__ cnt, int* __restrict__ start,
                            int* __restrict__ fill) {
    __shared__ int s[NCELL];
    int t = threadIdx.x;
    int v0 = cnt[t], v1 = cnt[t + 1024];
    s[t] = v0; s[t + 1024] = v1;
    __syncthreads();
    for (int off = 1; off < NCELL; off <<= 1) {
        int a0 = (t >= off) ? s[t - off] : 0;
        int i1 = t + 1024;
        int a1 = (i1 >= off) ? s[i1 - off] : 0;
        __syncthreads();
        s[t] += a0; s[i1] += a1;
        __syncthreads();
    }
    start[t] = s[t] - v0;                fill[t] = s[t] - v0;
    start[t + 1024] = s[t + 1024] - v1;  fill[t + 1024] = s[t + 1024] - v1;
    if (t == 1023) start[NCELL] = s[NCELL - 1];
}

// pq[slot] = (x, y, z, orig_index_as_float_bits)
__global__ void scatter_kernel(const float* __restrict__ pos, int* __restrict__ fill,
                               float4* __restrict__ pq) {
    int i = blockIdx.x * blockDim.x + threadIdx.x;
    if (i < N_PTS) {
        float px = pos[3*i], py = pos[3*i+1], pz = pos[3*i+2];
        int c = cell_of(px, py, pz);
        int slot = atomicAdd(&fill[c], 1);
        pq[slot] = make_float4(px, py, pz, __int_as_float(i));
    }
}

// ---------- FPS ----------
// 1024 threads = 16 waves; wave w OWNS cells [128w,128w+128) and their points.
// s_mind / s_sub / s_wlist are wave-private (DS in-order per wave => no
// barrier around them). Cross-wave data = 16 wave-bests in s_gb (double-
// buffered by iteration parity) => exactly ONE __syncthreads per iteration.
// B: 16-lane groups, 4 cells in flight per wave-round. Per-cell max via one
// ds_max_u64 slot. F: 2 cells/lane flag + ballot-rank compact own list.

__global__ __launch_bounds__(NTF) void fps_kernel(
        const float4* __restrict__ pq, const int* __restrict__ cstart,
        const float* __restrict__ pos, int* __restrict__ sel) {
    __shared__ float s_mind[N_PTS];                    // 128 KB (owner-private)
    __shared__ unsigned long long s_sub[NCELL];        // 16 KB (owner-private)
    __shared__ unsigned long long s_redw[NWF][8];      // 1 KB  (owner-private)
    __shared__ unsigned long long s_gb[2][NWF];        // cross-wave, dbuf
    __shared__ unsigned int s_wlist[NWF][128];         // 8 KB  (owner-private)

    const int tid  = threadIdx.x;
    const int lane = tid & 63;
    const int wid  = tid >> 6;
    const int g    = lane >> 4;     // 16-lane group 0..3
    const int gl   = lane & 15;
    const unsigned long long lmask_lt = (1ULL << lane) - 1ULL;

    for (int i = tid; i < N_PTS; i += NTF) s_mind[i] = INFINITY;
    if (tid == 0) sel[0] = 0;

    // own-cell descriptors & geometry (2 cells per lane)
    float lox[2], loy[2], loz[2];
    unsigned int ent[2];
    unsigned long long vb[2];       // per-cell best, persistent in registers
    bool fmask[2];
    #pragma unroll
    for (int k = 0; k < 2; ++k) {
        const int rest = lane + (k << 6);
        const int c = (wid << 7) | rest;
        const int ix = ((rest & 3) << 2) | (((wid >> 3) & 1) << 1) | (wid & 1);
        const int iy = (((rest >> 2) & 7) << 1) | ((wid >> 1) & 1);
        const int iz = ((rest >> 5) << 1) | ((wid >> 2) & 1);
        lox[k] = (float)ix * 0.0625f;
        loy[k] = (float)iy * 0.0625f;
        loz[k] = (float)iz * 0.125f;
        const int cs = cstart[c], ce = cstart[c + 1];
        int len = ce - cs; if (len > 511) len = 511;   // statistically impossible
        ent[k] = (unsigned)cs | ((unsigned)len << 15) | ((unsigned)rest << 24);
        // +inf sentinel => every nonempty cell flagged on iteration 1
        vb[k] = (ce > cs) ? ((0x7F800000ULL << 32) | 0x3FFFFFFFULL) : 0ULL;
    }

    int nfw = 0;
    float px = pos[0], py = pos[1], pz = pos[2];

    auto flag_assign = [&]() {
        unsigned int cnt = 0;
        #pragma unroll
        for (int k = 0; k < 2; ++k) {
            const float cm = __uint_as_float((unsigned)(vb[k] >> 32));
            float dx = fmaxf(fmaxf(lox[k] - px, px - (lox[k] + 0.0625f)), 0.0f);
            float dy = fmaxf(fmaxf(loy[k] - py, py - (loy[k] + 0.0625f)), 0.0f);
            float dz = fmaxf(fmaxf(loz[k] - pz, pz - (loz[k] + 0.125f)), 0.0f);
            float lb2 = dx * dx + dy * dy + dz * dz;
            bool fl = (lb2 * 0.999f < cm);             // conservative skip bound
            fmask[k] = fl;
            unsigned long long b = __ballot(fl);
            unsigned rank = cnt + (unsigned)__popcll(b & lmask_lt);
            if (fl) s_wlist[wid][rank] = ent[k];
            cnt += (unsigned)__popcll(b);
        }
        nfw = (int)cnt;
    };
    flag_assign();
    __syncthreads();     // covers s_mind init (striped across waves)

    for (int m = 1; m < M_SEL; ++m) {
        // ---- B: own flagged cells, 4 in flight (one per 16-lane group) ----
        if (lane < 8) s_redw[wid][lane] = 0ULL;
        for (int i = g; i < nfw; i += 4) {
            const unsigned e = s_wlist[wid][i];
            const int cs = (int)(e & 0x7FFFu);
            const int ce = cs + (int)((e >> 15) & 0x1FFu);
            const int c  = (wid << 7) | (int)(e >> 24);
            if (gl == 0) s_sub[c] = 0ULL;              // in-order before atomics
            for (int j = cs + gl; j < ce; j += 16) {
                const float4 q = pq[j];
                const float d2 = d2_exact(q.x, q.y, q.z, px, py, pz);
                const float old = s_mind[j];
                const float nv = d2 < old ? d2 : old;
                s_mind[j] = nv;
                atomicMax(&s_sub[c],
                          make_pk(nv, (unsigned)__float_as_int(q.w), (unsigned)j));
            }
        }

        // ---- D: consolidate own flagged cells, own-wave argmax (no barrier:
        //      all data owner-private, DS in-order per wave) ----
        if (fmask[0]) vb[0] = s_sub[(wid << 7) | lane];
        if (fmask[1]) vb[1] = s_sub[(wid << 7) | (lane + 64)];
        unsigned long long best = umax64(vb[0], vb[1]);
        atomicMax(&s_redw[wid][lane & 7], best);
        #pragma unroll
        for (int i = 0; i < 8; ++i) best = umax64(best, s_redw[wid][i]);
        if (lane == 0) s_gb[m & 1][wid] = best;

        __syncthreads();     // the ONE barrier: publish wave-bests

        // ---- E: global argmax over 16 wave-bests (replicated, cheap) ----
        unsigned long long gb = 0ULL;
        #pragma unroll
        for (int i = 0; i < NWF; ++i) gb = umax64(gb, s_gb[m & 1][i]);
        const unsigned orig = (~(unsigned)(gb >> 15)) & 0x7FFFu;
        const unsigned slot = (unsigned)gb & 0x7FFFu;
        if (tid == 0) sel[m] = (int)orig;
        const float4 qp = pq[slot];                    // L2-hot broadcast
        px = qp.x; py = qp.y; pz = qp.z;

        // ---- F: own flags + own list for next iteration ----
        flag_assign();
    }
}

// ---------- ball query: up-to-64 nearest in-radius (one wave / centroid) ----------

__global__ __launch_bounds__(256) void ballq_kernel(
        const float* __restrict__ pos,
        const float4* __restrict__ pq,
        const int* __restrict__ cstart, const int* __restrict__ sel,
        int* __restrict__ nbr, int* __restrict__ ncnt) {
    __shared__ float s_d2[4][CAP];
    __shared__ int   s_o[4][CAP];
    __shared__ int   s_cnt[4];

    const int wid  = threadIdx.x >> 6;
    const int lane = threadIdx.x & 63;
    const int m = blockIdx.x * 4 + wid;

    if (lane == 0) s_cnt[wid] = 0;
    __syncthreads();

    int sidx = sel[m];
    float cx = pos[3*sidx], cy = pos[3*sidx+1], cz = pos[3*sidx+2];
    int ix = iclamp((int)(cx * 16.0f), 15);
    int iy = iclamp((int)(cy * 16.0f), 15);
    int iz = iclamp((int)(cz * 8.0f), 7);
    const float r2 = (float)(0.08 * 0.08);

    // cells reachable within r=0.08: +-2 in x,y (0.0625), +-1 in z (0.125)
    for (int dz = -1; dz <= 1; ++dz) {
        int z = iz + dz; if (z < 0 || z > 7) continue;
        for (int dy = -2; dy <= 2; ++dy) {
            int y = iy + dy; if (y < 0 || y > 15) continue;
            for (int dx = -2; dx <= 2; ++dx) {
                int xx = ix + dx; if (xx < 0 || xx > 15) continue;
                int c = cell_idx(xx, y, z);
                int cs = cstart[c], ce = cstart[c + 1];
                for (int j = cs + lane; j < ce; j += 64) {
                    float4 q = pq[j];
                    float d2 = d2_exact(cx, cy, cz, q.x, q.y, q.z);
                    if (d2 <= r2) {
                        int slot = atomicAdd(&s_cnt[wid], 1);
                        if (slot < CAP) { s_d2[wid][slot] = d2; s_o[wid][slot] = __float_as_int(q.w); }
                    }
                }
            }
        }
    }
    __syncthreads();

    int cnt = s_cnt[wid];
    if (cnt > CAP) cnt = CAP;
    if (cnt <= K_NBR) {
        if (lane < cnt) nbr[m * K_NBR + lane] = s_o[wid][lane];
        if (lane == 0) ncnt[m] = cnt;
    } else {
        // exact (d2, orig-index) lexicographic rank -> keep 64 nearest (matches top_k)
        for (int i = lane; i < cnt; i += 64) {
            float d2 = s_d2[wid][i];
            int   o  = s_o[wid][i];
            int rank = 0;
            for (int j = 0; j < cnt; ++j) {
                float dj = s_d2[wid][j];
                int   oj = s_o[wid][j];
                rank += (dj < d2 || (dj == d2 && oj < o)) ? 1 : 0;
            }
            if (rank < K_NBR) nbr[m * K_NBR + rank] = o;
        }
        if (lane == 0) ncnt[m] = K_NBR;
    }
}

// ---------- PointConv MLP + masked max-pool (fp32, one block / centroid) ----------

__global__ __launch_bounds__(256) void mlp_kernel(
        const float* __restrict__ x, const float* __restrict__ pos,
        const float* __restrict__ W1, const float* __restrict__ b1,
        const float* __restrict__ W2, const float* __restrict__ b2,
        const int* __restrict__ sel, const int* __restrict__ nbr,
        const int* __restrict__ ncnt, float* __restrict__ out) {
    __shared__ __align__(16) float feat[64][68];   // 67 used + pad
    __shared__ __align__(16) float h[64][H_MID];
    __shared__ float part[2][H_MID];

    const int m = blockIdx.x;
    const int tid = threadIdx.x;
    const int cnt = ncnt[m];
    const int s = sel[m];
    float cx = pos[3*s], cy = pos[3*s+1], cz = pos[3*s+2];

    for (int i = tid; i < 64 * 68; i += 256) ((float*)feat)[i] = 0.0f;
    __syncthreads();

    for (int i = tid; i < cnt * F_IN; i += 256) {
        int k = i >> 6, f = i & 63;
        int j = nbr[m * K_NBR + k];
        feat[k][f] = x[(size_t)j * F_IN + f];
    }
    if (tid < 64 && tid < cnt) {
        int j = nbr[m * K_NBR + tid];
        feat[tid][64] = pos[3*j]     - cx;
        feat[tid][65] = pos[3*j + 1] - cy;
        feat[tid][66] = pos[3*j + 2] - cz;
    }
    __syncthreads();

    const int c = tid & 127;
    const int half = tid >> 7;

    for (int k = half; k < 64; k += 2) {
        float acc = b1[c];
        const float4* fr = (const float4*)&feat[k][0];
#pragma unroll
        for (int f4 = 0; f4 < 16; ++f4) {
            float4 fv = fr[f4];
            int fb = f4 * 4;
            acc = fmaf(fv.x, W1[(fb    ) * H_MID + c], acc);
            acc = fmaf(fv.y, W1[(fb + 1) * H_MID + c], acc);
            acc = fmaf(fv.z, W1[(fb + 2) * H_MID + c], acc);
            acc = fmaf(fv.w, W1[(fb + 3) * H_MID + c], acc);
        }
        acc = fmaf(feat[k][64], W1[64 * H_MID + c], acc);
        acc = fmaf(feat[k][65], W1[65 * H_MID + c], acc);
        acc = fmaf(feat[k][66], W1[66 * H_MID + c], acc);
        h[k][c] = fmaxf(acc, 0.0f);
    }
    __syncthreads();

    float best = -INFINITY;
    for (int k = half; k < cnt; k += 2) {
        float acc = 0.0f;
        const float4* hr = (const float4*)&h[k][0];
#pragma unroll
        for (int q = 0; q < 32; ++q) {
            float4 hv = hr[q];
            int hb = q * 4;
            acc = fmaf(hv.x, W2[(hb    ) * C_OUT + c], acc);
            acc = fmaf(hv.y, W2[(hb + 1) * C_OUT + c], acc);
            acc = fmaf(hv.z, W2[(hb + 2) * C_OUT + c], acc);
            acc = fmaf(hv.w, W2[(hb + 3) * C_OUT + c], acc);
        }
        best = fmaxf(best, acc);
    }
    part[half][c] = best;
    __syncthreads();
    if (tid < 128) {
        out[(size_t)m * C_OUT + tid] = fmaxf(part[0][tid], part[1][tid]) + b2[tid];
    }
}

// ---------- outputs 2 & 3 ----------

__global__ void tail_kernel(const float* __restrict__ pos, const int* __restrict__ sel,
                            float* __restrict__ out_selpos, float* __restrict__ out_batch) {
    int i = blockIdx.x * blockDim.x + threadIdx.x;
    if (i < M_SEL) {
        int s = sel[i];
        out_selpos[3*i]     = pos[3*s];
        out_selpos[3*i + 1] = pos[3*s + 1];
        out_selpos[3*i + 2] = pos[3*s + 2];
        out_batch[i] = 0.0f;
    }
}

// ---------- launch ----------

extern "C" void kernel_launch(void* const* d_in, const int* in_sizes, int n_in,
                              void* d_out, int out_size, void* d_ws, size_t ws_size,
                              hipStream_t stream) {
    const float* x   = (const float*)d_in[0];
    const float* pos = (const float*)d_in[1];
    // d_in[2] = batch (int64, all zeros) — unused
    const float* W1 = (const float*)d_in[3];
    const float* b1 = (const float*)d_in[4];
    const float* W2 = (const float*)d_in[5];
    const float* b2 = (const float*)d_in[6];

    float* out        = (float*)d_out;
    float* out_selpos = out + (size_t)M_SEL * C_OUT;
    float* out_batch  = out_selpos + (size_t)M_SEL * 3;

    char* ws = (char*)d_ws;
    size_t off = 0;
    auto alloc = [&](size_t bytes) -> void* {
        void* p = ws + off;
        off = (off + bytes + 255) & ~(size_t)255;
        return p;
    };
    int*    cnt    = (int*)alloc(NCELL * 4);
    int*    cstart = (int*)alloc((NCELL + 1) * 4);
    int*    cfill  = (int*)alloc(NCELL * 4);
    float4* pq     = (float4*)alloc((size_t)N_PTS * 16);
    int*    sel    = (int*)alloc(M_SEL * 4);
    int*    nbr    = (int*)alloc((size_t)M_SEL * K_NBR * 4);
    int*    ncnt   = (int*)alloc(M_SEL * 4);
    (void)ws_size; (void)in_sizes; (void)n_in; (void)out_size;

    (void)hipMemsetAsync(cnt, 0, NCELL * 4, stream);
    bin_count_kernel<<<N_PTS / 256, 256, 0, stream>>>(pos, cnt);
    scan_kernel<<<1, 1024, 0, stream>>>(cnt, cstart, cfill);
    scatter_kernel<<<N_PTS / 256, 256, 0, stream>>>(pos, cfill, pq);
    fps_kernel<<<1, NTF, 0, stream>>>(pq, cstart, pos, sel);
    ballq_kernel<<<M_SEL / 4, 256, 0, stream>>>(pos, pq, cstart, sel, nbr, ncnt);
    mlp_kernel<<<M_SEL, 256, 0, stream>>>(x, pos, W1, b1, W2, b2, sel, nbr, ncnt, out);
    tail_kernel<<<(M_SEL + 255) / 256, 256, 0, stream>>>(pos, sel, out_selpos, out_batch);
}

// Round 10
// 12611.777 us; speedup vs baseline: 2.5502x; 1.0308x over previous
//
#include <hip/hip_runtime.h>
#include <math.h>

#define N_PTS 32768
#define M_SEL 8192
#define K_NBR 64
#define F_IN  64
#define H_MID 128
#define C_OUT 128
#define NCELL 2048      // 16 x 16 x 8 grid, owner-swizzled cell index
#define CAP   192       // per-centroid candidate cap
#define NWF   8         // waves in fps block (one owner per wave)
#define NTF   (NWF * 64)

// ---------- helpers ----------

__device__ __forceinline__ int iclamp(int v, int hi) {
    return v < 0 ? 0 : (v > hi ? hi : v);
}

// owner-swizzled cell id: low bit of (ix,iy,iz) -> owner wave (8 waves),
// so any 3x3x3 spatial neighborhood spreads across all 8 waves.
__device__ __forceinline__ int cell_idx(int ix, int iy, int iz) {
    int w    = (ix & 1) | ((iy & 1) << 1) | ((iz & 1) << 2);
    int rest = ((iz >> 1) * 8 + (iy >> 1)) * 8 + (ix >> 1);      // [0,256)
    return (w << 8) | rest;
}

__device__ __forceinline__ int cell_of(float px, float py, float pz) {
    int ix = iclamp((int)(px * 16.0f), 15);
    int iy = iclamp((int)(py * 16.0f), 15);
    int iz = iclamp((int)(pz * 8.0f), 7);
    return cell_idx(ix, iy, iz);
}

// Bit-exact replica of numpy: ((dx*dx + dy*dy) + dz*dz), rn, no fma.
__device__ __forceinline__ float d2_exact(float ax, float ay, float az,
                                          float bx, float by, float bz) {
#pragma clang fp contract(off)
    float dx = ax - bx, dy = ay - by, dz = az - bz;
    return (dx * dx + dy * dy) + dz * dz;
}

__device__ __forceinline__ unsigned long long umax64(unsigned long long a,
                                                     unsigned long long b) {
    return a > b ? a : b;
}

// pack: [63:32] mind_bits, [29:15] orig^0x7FFF, [14:0] slot.
// Lex order = (mind, -orig); slot never decides (orig unique).
__device__ __forceinline__ unsigned long long make_pk(float nv, unsigned int o,
                                                      unsigned int slot) {
    return ((unsigned long long)__float_as_uint(nv) << 32)
         | ((unsigned long long)((o ^ 0x7FFFu) & 0x7FFFu) << 15)
         | (unsigned long long)slot;
}

// ---------- binning ----------

__global__ void bin_count_kernel(const float* __restrict__ pos, int* __restrict__ cnt) {
    int i = blockIdx.x * blockDim.x + threadIdx.x;
    if (i < N_PTS) {
        atomicAdd(&cnt[cell_of(pos[3*i], pos[3*i+1], pos[3*i+2])], 1);
    }
}

// inclusive Hillis-Steele over 2048 with 1024 threads (2 elements each)
__global__ void scan_kernel(const int* __restrict__ cnt, int* __restrict__ start,
                            int* __restrict__ fill) {
    __shared__ int s[NCELL];
    int t = threadIdx.x;
    int v0 = cnt[t], v1 = cnt[t + 1024];
    s[t] = v0; s[t + 1024] = v1;
    __syncthreads();
    for (int off = 1; off < NCELL; off <<= 1) {
        int a0 = (t >= off) ? s[t - off] : 0;
        int i1 = t + 1024;
        int a1 = (i1 >= off) ? s[i1 - off] : 0;
        __syncthreads();
        s[t] += a0; s[i1] += a1;
        __syncthreads();
    }
    start[t] = s[t] - v0;                fill[t] = s[t] - v0;
    start[t + 1024] = s[t + 1024] - v1;  fill[t + 1024] = s[t + 1024] - v1;
    if (t == 1023) start[NCELL] = s[NCELL - 1];
}

// pq[slot] = (x, y, z, orig_index_as_float_bits)
__global__ void scatter_kernel(const float* __restrict__ pos, int* __restrict__ fill,
                               float4* __restrict__ pq) {
    int i = blockIdx.x * blockDim.x + threadIdx.x;
    if (i < N_PTS) {
        float px = pos[3*i], py = pos[3*i+1], pz = pos[3*i+2];
        int c = cell_of(px, py, pz);
        int slot = atomicAdd(&fill[c], 1);
        pq[slot] = make_float4(px, py, pz, __int_as_float(i));
    }
}

// ---------- FPS ----------
// 512 threads = 8 waves (2/SIMD); wave w OWNS cells [256w,256w+256) and their
// points. s_mind / s_sub / s_wlist are wave-private (DS in-order per wave =>
// no barrier around them). Cross-wave data = 8 wave-bests in s_gb (double-
// buffered by iteration parity) => exactly ONE __syncthreads per iteration.
// B: 16-lane groups, 4 cells in flight per wave-round. Per-cell max via one
// ds_max_u64 slot. E: 4 x b128 reads + max tree. F: 4 cells/lane flag +
// ballot-rank compact own list.

__global__ __launch_bounds__(NTF) void fps_kernel(
        const float4* __restrict__ pq, const int* __restrict__ cstart,
        const float* __restrict__ pos, int* __restrict__ sel) {
    __shared__ float s_mind[N_PTS];                    // 128 KB (owner-private)
    __shared__ unsigned long long s_sub[NCELL];        // 16 KB (owner-private)
    __shared__ unsigned long long s_redw[NWF][8];      // 512 B (owner-private)
    __shared__ __align__(16) unsigned long long s_gb[2][NWF];  // cross-wave, dbuf
    __shared__ unsigned int s_wlist[NWF][256];         // 8 KB  (owner-private)

    const int tid  = threadIdx.x;
    const int lane = tid & 63;
    const int wid  = tid >> 6;
    const int g    = lane >> 4;     // 16-lane group 0..3
    const int gl   = lane & 15;
    const unsigned long long lmask_lt = (1ULL << lane) - 1ULL;

    for (int i = tid; i < N_PTS; i += NTF) s_mind[i] = INFINITY;
    if (tid == 0) sel[0] = 0;

    // own-cell descriptors & geometry (4 cells per lane)
    float lox[4], loy[4], loz[4];
    unsigned int ent[4];
    unsigned long long vb[4];       // per-cell best, persistent in registers
    bool fmask[4];
    #pragma unroll
    for (int k = 0; k < 4; ++k) {
        const int rest = lane + (k << 6);               // [0,256)
        const int c = (wid << 8) | rest;
        const int ix = ((rest & 7) << 1)        | (wid & 1);
        const int iy = (((rest >> 3) & 7) << 1) | ((wid >> 1) & 1);
        const int iz = ((rest >> 6) << 1)       | ((wid >> 2) & 1);
        lox[k] = (float)ix * 0.0625f;
        loy[k] = (float)iy * 0.0625f;
        loz[k] = (float)iz * 0.125f;
        const int cs = cstart[c], ce = cstart[c + 1];
        int len = ce - cs; if (len > 511) len = 511;   // statistically impossible
        ent[k] = (unsigned)cs | ((unsigned)len << 15) | ((unsigned)rest << 24);
        // +inf sentinel => every nonempty cell flagged on iteration 1
        vb[k] = (ce > cs) ? ((0x7F800000ULL << 32) | 0x3FFFFFFFULL) : 0ULL;
    }

    int nfw = 0;
    float px = pos[0], py = pos[1], pz = pos[2];

    auto flag_assign = [&]() {
        unsigned int cnt = 0;
        #pragma unroll
        for (int k = 0; k < 4; ++k) {
            const float cm = __uint_as_float((unsigned)(vb[k] >> 32));
            float dx = fmaxf(fmaxf(lox[k] - px, px - (lox[k] + 0.0625f)), 0.0f);
            float dy = fmaxf(fmaxf(loy[k] - py, py - (loy[k] + 0.0625f)), 0.0f);
            float dz = fmaxf(fmaxf(loz[k] - pz, pz - (loz[k] + 0.125f)), 0.0f);
            float lb2 = dx * dx + dy * dy + dz * dz;
            bool fl = (lb2 * 0.999f < cm);             // conservative skip bound
            fmask[k] = fl;
            unsigned long long b = __ballot(fl);
            unsigned rank = cnt + (unsigned)__popcll(b & lmask_lt);
            if (fl) s_wlist[wid][rank] = ent[k];
            cnt += (unsigned)__popcll(b);
        }
        nfw = (int)cnt;
    };
    flag_assign();
    __syncthreads();     // covers s_mind init (striped across waves)

    for (int m = 1; m < M_SEL; ++m) {
        // ---- B: own flagged cells, 4 in flight (one per 16-lane group) ----
        if (lane < 8) s_redw[wid][lane] = 0ULL;
        for (int i = g; i < nfw; i += 4) {
            const unsigned e = s_wlist[wid][i];
            const int cs = (int)(e & 0x7FFFu);
            const int ce = cs + (int)((e >> 15) & 0x1FFu);
            const int c  = (wid << 8) | (int)(e >> 24);
            if (gl == 0) s_sub[c] = 0ULL;              // in-order before atomics
            for (int j = cs + gl; j < ce; j += 16) {
                const float4 q = pq[j];
                const float d2 = d2_exact(q.x, q.y, q.z, px, py, pz);
                const float old = s_mind[j];
                const float nv = d2 < old ? d2 : old;
                s_mind[j] = nv;
                atomicMax(&s_sub[c],
                          make_pk(nv, (unsigned)__float_as_int(q.w), (unsigned)j));
            }
        }

        // ---- D: consolidate own flagged cells, own-wave argmax (no barrier:
        //      all data owner-private, DS in-order per wave) ----
        #pragma unroll
        for (int k = 0; k < 4; ++k)
            if (fmask[k]) vb[k] = s_sub[(wid << 8) | (lane + (k << 6))];
        unsigned long long best = umax64(umax64(vb[0], vb[1]),
                                         umax64(vb[2], vb[3]));
        atomicMax(&s_redw[wid][lane & 7], best);
        #pragma unroll
        for (int i = 0; i < 8; ++i) best = umax64(best, s_redw[wid][i]);
        if (lane == 0) s_gb[m & 1][wid] = best;

        __syncthreads();     // the ONE barrier: publish wave-bests

        // ---- E: global argmax over 8 wave-bests (4 x b128 + max tree) ----
        const ulonglong2* gp = (const ulonglong2*)&s_gb[m & 1][0];
        const ulonglong2 g0 = gp[0], g1 = gp[1], g2 = gp[2], g3 = gp[3];
        unsigned long long gb = umax64(
            umax64(umax64(g0.x, g0.y), umax64(g1.x, g1.y)),
            umax64(umax64(g2.x, g2.y), umax64(g3.x, g3.y)));
        const unsigned orig = (~(unsigned)(gb >> 15)) & 0x7FFFu;
        const unsigned slot = (unsigned)gb & 0x7FFFu;
        if (tid == 0) sel[m] = (int)orig;
        const float4 qp = pq[slot];                    // L1/L2-hot broadcast
        px = qp.x; py = qp.y; pz = qp.z;

        // ---- F: own flags + own list for next iteration ----
        flag_assign();
    }
}

// ---------- ball query: up-to-64 nearest in-radius (one wave / centroid) ----------

__global__ __launch_bounds__(256) void ballq_kernel(
        const float* __restrict__ pos,
        const float4* __restrict__ pq,
        const int* __restrict__ cstart, const int* __restrict__ sel,
        int* __restrict__ nbr, int* __restrict__ ncnt) {
    __shared__ float s_d2[4][CAP];
    __shared__ int   s_o[4][CAP];
    __shared__ int   s_cnt[4];

    const int wid  = threadIdx.x >> 6;
    const int lane = threadIdx.x & 63;
    const int m = blockIdx.x * 4 + wid;

    if (lane == 0) s_cnt[wid] = 0;
    __syncthreads();

    int sidx = sel[m];
    float cx = pos[3*sidx], cy = pos[3*sidx+1], cz = pos[3*sidx+2];
    int ix = iclamp((int)(cx * 16.0f), 15);
    int iy = iclamp((int)(cy * 16.0f), 15);
    int iz = iclamp((int)(cz * 8.0f), 7);
    const float r2 = (float)(0.08 * 0.08);

    // cells reachable within r=0.08: +-2 in x,y (0.0625), +-1 in z (0.125)
    for (int dz = -1; dz <= 1; ++dz) {
        int z = iz + dz; if (z < 0 || z > 7) continue;
        for (int dy = -2; dy <= 2; ++dy) {
            int y = iy + dy; if (y < 0 || y > 15) continue;
            for (int dx = -2; dx <= 2; ++dx) {
                int xx = ix + dx; if (xx < 0 || xx > 15) continue;
                int c = cell_idx(xx, y, z);
                int cs = cstart[c], ce = cstart[c + 1];
                for (int j = cs + lane; j < ce; j += 64) {
                    float4 q = pq[j];
                    float d2 = d2_exact(cx, cy, cz, q.x, q.y, q.z);
                    if (d2 <= r2) {
                        int slot = atomicAdd(&s_cnt[wid], 1);
                        if (slot < CAP) { s_d2[wid][slot] = d2; s_o[wid][slot] = __float_as_int(q.w); }
                    }
                }
            }
        }
    }
    __syncthreads();

    int cnt = s_cnt[wid];
    if (cnt > CAP) cnt = CAP;
    if (cnt <= K_NBR) {
        if (lane < cnt) nbr[m * K_NBR + lane] = s_o[wid][lane];
        if (lane == 0) ncnt[m] = cnt;
    } else {
        // exact (d2, orig-index) lexicographic rank -> keep 64 nearest (matches top_k)
        for (int i = lane; i < cnt; i += 64) {
            float d2 = s_d2[wid][i];
            int   o  = s_o[wid][i];
            int rank = 0;
            for (int j = 0; j < cnt; ++j) {
                float dj = s_d2[wid][j];
                int   oj = s_o[wid][j];
                rank += (dj < d2 || (dj == d2 && oj < o)) ? 1 : 0;
            }
            if (rank < K_NBR) nbr[m * K_NBR + rank] = o;
        }
        if (lane == 0) ncnt[m] = K_NBR;
    }
}

// ---------- PointConv MLP + masked max-pool (fp32, one block / centroid) ----------

__global__ __launch_bounds__(256) void mlp_kernel(
        const float* __restrict__ x, const float* __restrict__ pos,
        const float* __restrict__ W1, const float* __restrict__ b1,
        const float* __restrict__ W2, const float* __restrict__ b2,
        const int* __restrict__ sel, const int* __restrict__ nbr,
        const int* __restrict__ ncnt, float* __restrict__ out) {
    __shared__ __align__(16) float feat[64][68];   // 67 used + pad
    __shared__ __align__(16) float h[64][H_MID];
    __shared__ float part[2][H_MID];

    const int m = blockIdx.x;
    const int tid = threadIdx.x;
    const int cnt = ncnt[m];
    const int s = sel[m];
    float cx = pos[3*s], cy = pos[3*s+1], cz = pos[3*s+2];

    for (int i = tid; i < 64 * 68; i += 256) ((float*)feat)[i] = 0.0f;
    __syncthreads();

    for (int i = tid; i < cnt * F_IN; i += 256) {
        int k = i >> 6, f = i & 63;
        int j = nbr[m * K_NBR + k];
        feat[k][f] = x[(size_t)j * F_IN + f];
    }
    if (tid < 64 && tid < cnt) {
        int j = nbr[m * K_NBR + tid];
        feat[tid][64] = pos[3*j]     - cx;
        feat[tid][65] = pos[3*j + 1] - cy;
        feat[tid][66] = pos[3*j + 2] - cz;
    }
    __syncthreads();

    const int c = tid & 127;
    const int half = tid >> 7;

    for (int k = half; k < 64; k += 2) {
        float acc = b1[c];
        const float4* fr = (const float4*)&feat[k][0];
#pragma unroll
        for (int f4 = 0; f4 < 16; ++f4) {
            float4 fv = fr[f4];
            int fb = f4 * 4;
            acc = fmaf(fv.x, W1[(fb    ) * H_MID + c], acc);
            acc = fmaf(fv.y, W1[(fb + 1) * H_MID + c], acc);
            acc = fmaf(fv.z, W1[(fb + 2) * H_MID + c], acc);
            acc = fmaf(fv.w, W1[(fb + 3) * H_MID + c], acc);
        }
        acc = fmaf(feat[k][64], W1[64 * H_MID + c], acc);
        acc = fmaf(feat[k][65], W1[65 * H_MID + c], acc);
        acc = fmaf(feat[k][66], W1[66 * H_MID + c], acc);
        h[k][c] = fmaxf(acc, 0.0f);
    }
    __syncthreads();

    float best = -INFINITY;
    for (int k = half; k < cnt; k += 2) {
        float acc = 0.0f;
        const float4* hr = (const float4*)&h[k][0];
#pragma unroll
        for (int q = 0; q < 32; ++q) {
            float4 hv = hr[q];
            int hb = q * 4;
            acc = fmaf(hv.x, W2[(hb    ) * C_OUT + c], acc);
            acc = fmaf(hv.y, W2[(hb + 1) * C_OUT + c], acc);
            acc = fmaf(hv.z, W2[(hb + 2) * C_OUT + c], acc);
            acc = fmaf(hv.w, W2[(hb + 3) * C_OUT + c], acc);
        }
        best = fmaxf(best, acc);
    }
    part[half][c] = best;
    __syncthreads();
    if (tid < 128) {
        out[(size_t)m * C_OUT + tid] = fmaxf(part[0][tid], part[1][tid]) + b2[tid];
    }
}

// ---------- outputs 2 & 3 ----------

__global__ void tail_kernel(const float* __restrict__ pos, const int* __restrict__ sel,
                            float* __restrict__ out_selpos, float* __restrict__ out_batch) {
    int i = blockIdx.x * blockDim.x + threadIdx.x;
    if (i < M_SEL) {
        int s = sel[i];
        out_selpos[3*i]     = pos[3*s];
        out_selpos[3*i + 1] = pos[3*s + 1];
        out_selpos[3*i + 2] = pos[3*s + 2];
        out_batch[i] = 0.0f;
    }
}

// ---------- launch ----------

extern "C" void kernel_launch(void* const* d_in, const int* in_sizes, int n_in,
                              void* d_out, int out_size, void* d_ws, size_t ws_size,
                              hipStream_t stream) {
    const float* x   = (const float*)d_in[0];
    const float* pos = (const float*)d_in[1];
    // d_in[2] = batch (int64, all zeros) — unused
    const float* W1 = (const float*)d_in[3];
    const float* b1 = (const float*)d_in[4];
    const float* W2 = (const float*)d_in[5];
    const float* b2 = (const float*)d_in[6];

    float* out        = (float*)d_out;
    float* out_selpos = out + (size_t)M_SEL * C_OUT;
    float* out_batch  = out_selpos + (size_t)M_SEL * 3;

    char* ws = (char*)d_ws;
    size_t off = 0;
    auto alloc = [&](size_t bytes) -> void* {
        void* p = ws + off;
        off = (off + bytes + 255) & ~(size_t)255;
        return p;
    };
    int*    cnt    = (int*)alloc(NCELL * 4);
    int*    cstart = (int*)alloc((NCELL + 1) * 4);
    int*    cfill  = (int*)alloc(NCELL * 4);
    float4* pq     = (float4*)alloc((size_t)N_PTS * 16);
    int*    sel    = (int*)alloc(M_SEL * 4);
    int*    nbr    = (int*)alloc((size_t)M_SEL * K_NBR * 4);
    int*    ncnt   = (int*)alloc(M_SEL * 4);
    (void)ws_size; (void)in_sizes; (void)n_in; (void)out_size;

    (void)hipMemsetAsync(cnt, 0, NCELL * 4, stream);
    bin_count_kernel<<<N_PTS / 256, 256, 0, stream>>>(pos, cnt);
    scan_kernel<<<1, 1024, 0, stream>>>(cnt, cstart, cfill);
    scatter_kernel<<<N_PTS / 256, 256, 0, stream>>>(pos, cfill, pq);
    fps_kernel<<<1, NTF, 0, stream>>>(pq, cstart, pos, sel);
    ballq_kernel<<<M_SEL / 4, 256, 0, stream>>>(pos, pq, cstart, sel, nbr, ncnt);
    mlp_kernel<<<M_SEL, 256, 0, stream>>>(x, pos, W1, b1, W2, b2, sel, nbr, ncnt, out);
    tail_kernel<<<(M_SEL + 255) / 256, 256, 0, stream>>>(pos, sel, out_selpos, out_batch);
}